// Round 22
// baseline (169.662 us; speedup 1.0000x reference)
//
#include <hip/hip_runtime.h>
#include <hip/hip_fp16.h>

// Symmetric pair-weight recurrent net, T=8192, 8 steps of s = tanh(M s + b).
// M symmetric, zero diagonal; stored ONLY as strict upper triangle in fp16.
// Layout: row starts padded to 64-half (128B) boundaries so conv's vector
// stores write COMPLETE cache lines: slot(r,j) = crow64(r) + j (j > r).
// conv: row-wise contiguous streaming; NONTEMPORAL w16 stores (write stream
// bypasses cache allocation). sym (R14 body): each pair weight read ONCE per
// pass, both directions accumulated; state staged as tanh(y_prev+b).

constexpr int T     = 8192;
constexpr int IN    = 2048;
constexpr int OUT   = 1024;
constexpr int NPROP = 8;

constexpr int TILE   = 128;
constexpr int NT     = T / TILE;              // 64
constexpr int NTILES = NT * (NT + 1) / 2;     // 2080

typedef unsigned int vu4 __attribute__((ext_vector_type(4)));

// f32 source triangle index (j > r)
__device__ __forceinline__ unsigned triidx(unsigned r, unsigned j) {
    return r * (unsigned)(T - 1) - ((r * (r - 1u)) >> 1) + j - r - 1u;
}

// fp16 padded-triangle row base (halves), 128B-aligned:
//   crow64(r) = r*T - 64*S(r), S(r) = 32*a*(a-1) + a*(b+1), a=r>>6, b=r&63.
// Row r's valid slots: [crow64(r)+r+1, crow64(r)+T). Write set injective
// across rows; sub-/on-diagonal slots alias other rows (read-only + masked
// in sym, NEVER stored).
__device__ __forceinline__ int crow64(int r) {
    int a = r >> 6, b = r & 63;
    return r * T - 64 * (32 * a * (a - 1) + a * (b + 1));
}
constexpr size_t W16_ALLOC = 33816576;   // crow64(8191)+8192; %8==0

__host__ __device__ __forceinline__ unsigned rowstart(int b) {
    return (unsigned)(b * NT) - (unsigned)((b * (b - 1)) >> 1);
}

__device__ __forceinline__ void tile_decode(unsigned p, int& bi, int& bj) {
    const float A = (float)(2 * NT + 1);      // 129
    bi = (int)((A - sqrtf(A * A - 8.0f * (float)p)) * 0.5f);
    if (bi < 0) bi = 0;
    while (rowstart(bi + 1) <= p) ++bi;
    while (rowstart(bi) > p) --bi;
    bj = bi + (int)(p - rowstart(bi));
}

__device__ __forceinline__ vu4 pack8v(const float* v) {
    vu4 pk;
    #pragma unroll
    for (int d = 0; d < 4; ++d) {
        unsigned lo = __half_as_ushort(__float2half_rn(v[2 * d]));
        unsigned hi = __half_as_ushort(__float2half_rn(v[2 * d + 1]));
        pk[d] = lo | (hi << 16);
    }
    return pk;
}

__device__ __forceinline__ void sel8(float4 fA, float4 fB, float4 fC, int sel,
                                     float* v) {
    if (sel == 0) {
        v[0]=fA.x; v[1]=fA.y; v[2]=fA.z; v[3]=fA.w;
        v[4]=fB.x; v[5]=fB.y; v[6]=fB.z; v[7]=fB.w;
    } else if (sel == 1) {
        v[0]=fA.y; v[1]=fA.z; v[2]=fA.w; v[3]=fB.x;
        v[4]=fB.y; v[5]=fB.z; v[6]=fB.w; v[7]=fC.x;
    } else if (sel == 2) {
        v[0]=fA.z; v[1]=fA.w; v[2]=fB.x; v[3]=fB.y;
        v[4]=fB.z; v[5]=fB.w; v[6]=fC.x; v[7]=fC.y;
    } else {
        v[0]=fA.w; v[1]=fB.x; v[2]=fB.y; v[3]=fB.z;
        v[4]=fB.w; v[5]=fC.x; v[6]=fC.y; v[7]=fC.z;
    }
}

// ---- one-time f32 triangle -> fp16 padded triangle, ROW-WISE streaming ----
// Block b handles rows b and 8191-b. Head (to the 64-half boundary)
// elementwise; then threads stride aligned 8-half chunks — every 8-thread
// group writes one complete 128B line, nontemporally.
__global__ __launch_bounds__(256) void conv_kernel(const float* __restrict__ w,
                                                   __half* __restrict__ w16) {
    int t = threadIdx.x;
    #pragma unroll
    for (int q = 0; q < 2; ++q) {
        int r = (q == 0) ? (int)blockIdx.x : (T - 1 - (int)blockIdx.x);
        int j1 = r + 1;
        int jA = (j1 + 63) & ~63;               // first 128B-aligned chunk col
        unsigned offr = triidx((unsigned)r, (unsigned)j1);  // row start in w
        int cr = crow64(r);
        if (t < jA - j1)                        // head (<64 elems)
            w16[cr + j1 + t] = __float2half_rn(w[offr + (unsigned)t]);
        if (jA >= T) continue;
        unsigned baseA = offr + (unsigned)(jA - j1);        // triidx(r, jA)
        int sel = (int)(baseA & 3u);            // uniform per row
        for (int j8 = jA + t * 8; j8 + 8 <= T; j8 += 8 * 256) {
            unsigned a0 = (baseA + (unsigned)(j8 - jA)) & ~3u;
            float4 fA = *(const float4*)(w + a0);
            float4 fB = *(const float4*)(w + a0 + 4);
            float4 fC = *(const float4*)(w + a0 + 8);
            float v[8];
            sel8(fA, fB, fC, sel, v);
            __builtin_nontemporal_store(pack8v(v), (vu4*)(w16 + (cr + j8)));
        }
    }
}

// init: build s0 (raw initial state, no tanh) and zero the 8 y accumulators.
__global__ __launch_bounds__(256) void init_kernel(const float* __restrict__ in,
                                                   float* __restrict__ s0,
                                                   float* __restrict__ y) {
    int n = blockIdx.x * 256 + threadIdx.x;
    if (n < T) s0[n] = (n < IN) ? in[n] : 0.0f;
    if (n < NPROP * T) y[n] = 0.0f;
}

// ---- fused symmetric tile pass (R14 body) ----
// mode 0: full. mode 1: iter1 (grid 904, bi<16; row side live only bj<16).
// mode 2: iter8 (only y[7168..] live).
// State: sp ? sp[idx] : tanh(yprev[idx] + bv[idx]).
__global__ __launch_bounds__(256) void sym_kernel(const __half* __restrict__ w16,
                                                  const float* __restrict__ sp,
                                                  const float* __restrict__ yprev,
                                                  const float* __restrict__ bv,
                                                  float* __restrict__ y, int mode) {
    __shared__ float sIl[TILE], sJl[TILE];
    __shared__ float colpart[4][TILE];

    int bi, bj; tile_decode(blockIdx.x, bi, bj);
    if (mode == 2 && bj < (T - OUT) / TILE) return;    // iter8: only y[7168..]
    bool doRow = (mode == 0) ? true
               : (mode == 1) ? (bj < IN / TILE)
                             : (bi >= (T - OUT) / TILE);

    int i0 = bi * TILE, j0 = bj * TILE;
    int t = threadIdx.x;
    {
        int idx = (t < TILE) ? (i0 + t) : (j0 + (t - TILE));
        float sval = sp ? sp[idx] : tanhf(yprev[idx] + bv[idx]);
        if (t < TILE) sIl[t] = sval;
        else          sJl[t - TILE] = sval;
    }
    __syncthreads();

    int l = t & 63, wv = t >> 6;
    int g = l & 15, ro = l >> 4;
    int cbase = j0 + g * 8;

    float sjv[8];
    #pragma unroll
    for (int d = 0; d < 8; ++d) sjv[d] = sJl[g * 8 + d];
    float colacc[8] = {0.f, 0.f, 0.f, 0.f, 0.f, 0.f, 0.f, 0.f};

    #pragma unroll
    for (int k = 0; k < 8; ++k) {
        int rr = wv * 32 + k * 4 + ro;
        int r  = i0 + rr;
        // aligned uint4: crow64(r)%64==0, cbase%8==0. Sub-diagonal slots in
        // diag tiles read in-allocation garbage and are masked below.
        uint4 wq = *(const uint4*)(w16 + (crow64(r) + cbase));
        const __half2* h2 = (const __half2*)&wq;
        float2 f0 = __half22float2(h2[0]);
        float2 f1 = __half22float2(h2[1]);
        float2 f2 = __half22float2(h2[2]);
        float2 f3 = __half22float2(h2[3]);
        float wf[8] = {f0.x, f0.y, f1.x, f1.y, f2.x, f2.y, f3.x, f3.y};

        float si = sIl[rr];
        float rp = 0.0f;
        #pragma unroll
        for (int d = 0; d < 8; ++d) {
            float we = (cbase + d > r) ? wf[d] : 0.0f;   // strict upper only
            colacc[d] = fmaf(we, si, colacc[d]);
            rp        = fmaf(we, sjv[d], rp);
        }
        if (doRow) {
            rp += __shfl_xor(rp, 1, 64);
            rp += __shfl_xor(rp, 2, 64);
            rp += __shfl_xor(rp, 4, 64);
            rp += __shfl_xor(rp, 8, 64);
            if (g == 0) atomicAdd(&y[r], rp);
        }
    }

    #pragma unroll
    for (int d = 0; d < 8; ++d) {
        colacc[d] += __shfl_xor(colacc[d], 16, 64);
        colacc[d] += __shfl_xor(colacc[d], 32, 64);
    }
    if (l < 16) {
        #pragma unroll
        for (int d = 0; d < 8; ++d) colpart[wv][g * 8 + d] = colacc[d];
    }
    __syncthreads();
    if (t < TILE) {
        float c = colpart[0][t] + colpart[1][t] + colpart[2][t] + colpart[3][t];
        atomicAdd(&y[j0 + t], c);
    }
}

__global__ __launch_bounds__(256) void actout_kernel(const float* __restrict__ b,
                                                     const float* __restrict__ y,
                                                     float* __restrict__ o) {
    int n = blockIdx.x * 256 + threadIdx.x;
    if (n < OUT) o[n] = tanhf(y[T - OUT + n] + b[T - OUT + n]);
}

extern "C" void kernel_launch(void* const* d_in, const int* in_sizes, int n_in,
                              void* d_out, int out_size, void* d_ws, size_t ws_size,
                              hipStream_t stream) {
    const float* in = (const float*)d_in[0];   // inputs [2048]
    const float* w  = (const float*)d_in[1];   // w_flat [T*(T-1)/2] f32
    const float* b  = (const float*)d_in[2];   // b [8192] f32
    float* out = (float*)d_out;                // [1024] f32

    __half* w16 = (__half*)d_ws;                               // 67.63 MB
    float*  s0  = (float*)((char*)d_ws + W16_ALLOC * sizeof(__half));
    float*  y   = s0 + T;                      // 8 accumulators, y + it*T

    conv_kernel<<<T / 2, 256, 0, stream>>>(w, w16);
    init_kernel<<<NPROP * T / 256, 256, 0, stream>>>(in, s0, y);

    // iter 1: tiles bi<16 (contiguous p < 904); state = s0 (no tanh)
    sym_kernel<<<rowstart(IN / TILE), 256, 0, stream>>>(w16, s0, nullptr, nullptr,
                                                        y, 1);
    // iters 2..7: state = tanh(y[it-2] + b), accumulate into y[it-1]
    for (int it = 1; it < NPROP - 1; ++it) {
        sym_kernel<<<NTILES, 256, 0, stream>>>(w16, nullptr, y + (it - 1) * T, b,
                                               y + it * T, 0);
    }
    // iter 8: only outputs 7168.. needed
    sym_kernel<<<NTILES, 256, 0, stream>>>(w16, nullptr, y + (NPROP - 2) * T, b,
                                           y + (NPROP - 1) * T, 2);
    actout_kernel<<<OUT / 256, 256, 0, stream>>>(b, y + (NPROP - 1) * T, out);
}

// Round 23
// 168.503 us; speedup vs baseline: 1.0069x; 1.0069x over previous
//
#include <hip/hip_runtime.h>
#include <hip/hip_fp16.h>

// Symmetric pair-weight recurrent net, T=8192, 8 steps of s = tanh(M s + b).
// M symmetric, zero diagonal; stored ONLY as strict upper triangle in fp16.
// Layout: row starts padded to 64-half (128B) boundaries:
//   slot(r,j) = crow64(r) + j (j > r), crow64(r) % 64 == 0.
// conv v6: LDS-staged two-phase. Phase A: read f32 + convert into LDS (global
// loads can't alias LDS stores -> compiler streams them). Phase B: LDS ->
// global, full-line coalesced stores. sym (R14 body): each pair weight read
// ONCE per pass, both directions accumulated; tanh staging fused.

constexpr int T     = 8192;
constexpr int IN    = 2048;
constexpr int OUT   = 1024;
constexpr int NPROP = 8;

constexpr int TILE   = 128;
constexpr int NT     = T / TILE;              // 64
constexpr int NTILES = NT * (NT + 1) / 2;     // 2080

typedef unsigned int vu4 __attribute__((ext_vector_type(4)));

// f32 source triangle index (j > r)
__device__ __forceinline__ unsigned triidx(unsigned r, unsigned j) {
    return r * (unsigned)(T - 1) - ((r * (r - 1u)) >> 1) + j - r - 1u;
}

// fp16 padded-triangle row base (halves), 128B-aligned:
//   crow64(r) = r*T - 64*S(r), S(r) = 32*a*(a-1) + a*(b+1), a=r>>6, b=r&63.
// Row r's valid slots: [crow64(r)+r+1, crow64(r)+T). Write set injective
// across rows; sub-/on-diagonal slots alias other rows (read-only + masked
// in sym, NEVER stored).
__device__ __forceinline__ int crow64(int r) {
    int a = r >> 6, b = r & 63;
    return r * T - 64 * (32 * a * (a - 1) + a * (b + 1));
}
constexpr size_t W16_ALLOC = 33816576;   // crow64(8191)+8192; %8==0

__host__ __device__ __forceinline__ unsigned rowstart(int b) {
    return (unsigned)(b * NT) - (unsigned)((b * (b - 1)) >> 1);
}

__device__ __forceinline__ void tile_decode(unsigned p, int& bi, int& bj) {
    const float A = (float)(2 * NT + 1);      // 129
    bi = (int)((A - sqrtf(A * A - 8.0f * (float)p)) * 0.5f);
    if (bi < 0) bi = 0;
    while (rowstart(bi + 1) <= p) ++bi;
    while (rowstart(bi) > p) --bi;
    bj = bi + (int)(p - rowstart(bi));
}

__device__ __forceinline__ vu4 pack8v(const float* v) {
    vu4 pk;
    #pragma unroll
    for (int d = 0; d < 4; ++d) {
        unsigned lo = __half_as_ushort(__float2half_rn(v[2 * d]));
        unsigned hi = __half_as_ushort(__float2half_rn(v[2 * d + 1]));
        pk[d] = lo | (hi << 16);
    }
    return pk;
}

__device__ __forceinline__ void sel8(float4 fA, float4 fB, float4 fC, int sel,
                                     float* v) {
    if (sel == 0) {
        v[0]=fA.x; v[1]=fA.y; v[2]=fA.z; v[3]=fA.w;
        v[4]=fB.x; v[5]=fB.y; v[6]=fB.z; v[7]=fB.w;
    } else if (sel == 1) {
        v[0]=fA.y; v[1]=fA.z; v[2]=fA.w; v[3]=fB.x;
        v[4]=fB.y; v[5]=fB.z; v[6]=fB.w; v[7]=fC.x;
    } else if (sel == 2) {
        v[0]=fA.z; v[1]=fA.w; v[2]=fB.x; v[3]=fB.y;
        v[4]=fB.z; v[5]=fB.w; v[6]=fC.x; v[7]=fC.y;
    } else {
        v[0]=fA.w; v[1]=fB.x; v[2]=fB.y; v[3]=fB.z;
        v[4]=fB.w; v[5]=fC.x; v[6]=fC.y; v[7]=fC.z;
    }
}

// ---- one-time f32 triangle -> fp16 padded triangle, LDS-staged ----
// Block b owns rows b and 8191-b (combined vector length <= 8191 halves).
// Phase A: f32 read + convert -> LDS (loads stream; no global-store hazard).
// Phase B: LDS -> w16, full-128B-line coalesced vu4 stores.
__global__ __launch_bounds__(256) void conv_kernel(const float* __restrict__ w,
                                                   __half* __restrict__ w16) {
    __shared__ vu4 lds[2][1024];               // 32 KB: one row each
    int t = threadIdx.x;
    int rows[2] = {(int)blockIdx.x, T - 1 - (int)blockIdx.x};

    // ---- phase A ----
    #pragma unroll
    for (int q = 0; q < 2; ++q) {
        int r = rows[q];
        int j1 = r + 1;
        int jA = (j1 + 63) & ~63;               // first 128B-aligned chunk col
        unsigned offr = triidx((unsigned)r, (unsigned)j1);
        if (t < jA - j1)                        // head (<64 elems), direct
            w16[crow64(r) + j1 + t] = __float2half_rn(w[offr + (unsigned)t]);
        if (jA >= T) continue;
        unsigned baseA = offr + (unsigned)(jA - j1);        // triidx(r, jA)
        int sel = (int)(baseA & 3u);            // uniform per row
        #pragma unroll 4
        for (int j8 = jA + t * 8; j8 < T; j8 += 8 * 256) {
            unsigned a0 = (baseA + (unsigned)(j8 - jA)) & ~3u;
            float4 fA = *(const float4*)(w + a0);
            float4 fB = *(const float4*)(w + a0 + 4);
            float4 fC = *(const float4*)(w + a0 + 8);
            float v[8];
            sel8(fA, fB, fC, sel, v);
            lds[q][(j8 - jA) >> 3] = pack8v(v);
        }
    }
    __syncthreads();

    // ---- phase B ----
    #pragma unroll
    for (int q = 0; q < 2; ++q) {
        int r = rows[q];
        int jA = ((r + 1) + 63) & ~63;
        int cr = crow64(r);
        int nch = (T - jA) >> 3;                // vu4 chunks in this row
        for (int k = t; k < nch; k += 256)
            *(vu4*)(w16 + cr + jA + k * 8) = lds[q][k];
    }
}

// init: build s0 (raw initial state, no tanh) and zero the 8 y accumulators.
__global__ __launch_bounds__(256) void init_kernel(const float* __restrict__ in,
                                                   float* __restrict__ s0,
                                                   float* __restrict__ y) {
    int n = blockIdx.x * 256 + threadIdx.x;
    if (n < T) s0[n] = (n < IN) ? in[n] : 0.0f;
    if (n < NPROP * T) y[n] = 0.0f;
}

// ---- fused symmetric tile pass (R14 body) ----
// mode 0: full. mode 1: iter1 (grid 904, bi<16; row side live only bj<16).
// mode 2: iter8 (only y[7168..] live).
// State: sp ? sp[idx] : tanh(yprev[idx] + bv[idx]).
__global__ __launch_bounds__(256) void sym_kernel(const __half* __restrict__ w16,
                                                  const float* __restrict__ sp,
                                                  const float* __restrict__ yprev,
                                                  const float* __restrict__ bv,
                                                  float* __restrict__ y, int mode) {
    __shared__ float sIl[TILE], sJl[TILE];
    __shared__ float colpart[4][TILE];

    int bi, bj; tile_decode(blockIdx.x, bi, bj);
    if (mode == 2 && bj < (T - OUT) / TILE) return;    // iter8: only y[7168..]
    bool doRow = (mode == 0) ? true
               : (mode == 1) ? (bj < IN / TILE)
                             : (bi >= (T - OUT) / TILE);

    int i0 = bi * TILE, j0 = bj * TILE;
    int t = threadIdx.x;
    {
        int idx = (t < TILE) ? (i0 + t) : (j0 + (t - TILE));
        float sval = sp ? sp[idx] : tanhf(yprev[idx] + bv[idx]);
        if (t < TILE) sIl[t] = sval;
        else          sJl[t - TILE] = sval;
    }
    __syncthreads();

    int l = t & 63, wv = t >> 6;
    int g = l & 15, ro = l >> 4;
    int cbase = j0 + g * 8;

    float sjv[8];
    #pragma unroll
    for (int d = 0; d < 8; ++d) sjv[d] = sJl[g * 8 + d];
    float colacc[8] = {0.f, 0.f, 0.f, 0.f, 0.f, 0.f, 0.f, 0.f};

    #pragma unroll
    for (int k = 0; k < 8; ++k) {
        int rr = wv * 32 + k * 4 + ro;
        int r  = i0 + rr;
        // aligned uint4: crow64(r)%64==0, cbase%8==0. Sub-diagonal slots in
        // diag tiles read in-allocation garbage and are masked below.
        uint4 wq = *(const uint4*)(w16 + (crow64(r) + cbase));
        const __half2* h2 = (const __half2*)&wq;
        float2 f0 = __half22float2(h2[0]);
        float2 f1 = __half22float2(h2[1]);
        float2 f2 = __half22float2(h2[2]);
        float2 f3 = __half22float2(h2[3]);
        float wf[8] = {f0.x, f0.y, f1.x, f1.y, f2.x, f2.y, f3.x, f3.y};

        float si = sIl[rr];
        float rp = 0.0f;
        #pragma unroll
        for (int d = 0; d < 8; ++d) {
            float we = (cbase + d > r) ? wf[d] : 0.0f;   // strict upper only
            colacc[d] = fmaf(we, si, colacc[d]);
            rp        = fmaf(we, sjv[d], rp);
        }
        if (doRow) {
            rp += __shfl_xor(rp, 1, 64);
            rp += __shfl_xor(rp, 2, 64);
            rp += __shfl_xor(rp, 4, 64);
            rp += __shfl_xor(rp, 8, 64);
            if (g == 0) atomicAdd(&y[r], rp);
        }
    }

    #pragma unroll
    for (int d = 0; d < 8; ++d) {
        colacc[d] += __shfl_xor(colacc[d], 16, 64);
        colacc[d] += __shfl_xor(colacc[d], 32, 64);
    }
    if (l < 16) {
        #pragma unroll
        for (int d = 0; d < 8; ++d) colpart[wv][g * 8 + d] = colacc[d];
    }
    __syncthreads();
    if (t < TILE) {
        float c = colpart[0][t] + colpart[1][t] + colpart[2][t] + colpart[3][t];
        atomicAdd(&y[j0 + t], c);
    }
}

__global__ __launch_bounds__(256) void actout_kernel(const float* __restrict__ b,
                                                     const float* __restrict__ y,
                                                     float* __restrict__ o) {
    int n = blockIdx.x * 256 + threadIdx.x;
    if (n < OUT) o[n] = tanhf(y[T - OUT + n] + b[T - OUT + n]);
}

extern "C" void kernel_launch(void* const* d_in, const int* in_sizes, int n_in,
                              void* d_out, int out_size, void* d_ws, size_t ws_size,
                              hipStream_t stream) {
    const float* in = (const float*)d_in[0];   // inputs [2048]
    const float* w  = (const float*)d_in[1];   // w_flat [T*(T-1)/2] f32
    const float* b  = (const float*)d_in[2];   // b [8192] f32
    float* out = (float*)d_out;                // [1024] f32

    __half* w16 = (__half*)d_ws;                               // 67.63 MB
    float*  s0  = (float*)((char*)d_ws + W16_ALLOC * sizeof(__half));
    float*  y   = s0 + T;                      // 8 accumulators, y + it*T

    conv_kernel<<<T / 2, 256, 0, stream>>>(w, w16);
    init_kernel<<<NPROP * T / 256, 256, 0, stream>>>(in, s0, y);

    // iter 1: tiles bi<16 (contiguous p < 904); state = s0 (no tanh)
    sym_kernel<<<rowstart(IN / TILE), 256, 0, stream>>>(w16, s0, nullptr, nullptr,
                                                        y, 1);
    // iters 2..7: state = tanh(y[it-2] + b), accumulate into y[it-1]
    for (int it = 1; it < NPROP - 1; ++it) {
        sym_kernel<<<NTILES, 256, 0, stream>>>(w16, nullptr, y + (it - 1) * T, b,
                                               y + it * T, 0);
    }
    // iter 8: only outputs 7168.. needed
    sym_kernel<<<NTILES, 256, 0, stream>>>(w16, nullptr, y + (NPROP - 2) * T, b,
                                           y + (NPROP - 1) * T, 2);
    actout_kernel<<<OUT / 256, 256, 0, stream>>>(b, y + (NPROP - 1) * T, out);
}

// Round 24
// 167.002 us; speedup vs baseline: 1.0159x; 1.0090x over previous
//
#include <hip/hip_runtime.h>
#include <hip/hip_fp16.h>

// Symmetric pair-weight recurrent net, T=8192, 8 steps of s = tanh(M s + b).
// M symmetric, zero diagonal; stored ONLY as strict upper triangle in fp16.
// Layout: row starts padded to 64-half (128B) boundaries so conv's vector
// stores write COMPLETE cache lines: slot(r,j) = crow64(r) + j (j > r).
// conv (R20): row-wise contiguous streaming, full-line stores.
// sym (R14 body): each pair weight read ONCE per pass, both directions
// accumulated; state staged as tanh(y_prev+b) on the fly.
// iter 8 launches ONLY the 484 working tiles (bj >= 56) via compact decode.

constexpr int T     = 8192;
constexpr int IN    = 2048;
constexpr int OUT   = 1024;
constexpr int NPROP = 8;

constexpr int TILE   = 128;
constexpr int NT     = T / TILE;              // 64
constexpr int NTILES = NT * (NT + 1) / 2;     // 2080
constexpr int BI8    = (T - OUT) / TILE;      // 56
constexpr int N8     = BI8 * (NT - BI8) + (NT - BI8) * (NT - BI8 + 1) / 2; // 484

// f32 source triangle index (j > r)
__device__ __forceinline__ unsigned triidx(unsigned r, unsigned j) {
    return r * (unsigned)(T - 1) - ((r * (r - 1u)) >> 1) + j - r - 1u;
}

// fp16 padded-triangle row base (halves), 128B-aligned:
//   crow64(r) = r*T - 64*S(r), S(r) = 32*a*(a-1) + a*(b+1), a=r>>6, b=r&63.
// Row r's valid slots: [crow64(r)+r+1, crow64(r)+T). Write set injective
// across rows; sub-/on-diagonal slots alias other rows (read-only + masked
// in sym, NEVER stored).
__device__ __forceinline__ int crow64(int r) {
    int a = r >> 6, b = r & 63;
    return r * T - 64 * (32 * a * (a - 1) + a * (b + 1));
}
constexpr size_t W16_ALLOC = 33816576;   // crow64(8191)+8192; %8==0

__host__ __device__ __forceinline__ unsigned rowstart(int b) {
    return (unsigned)(b * NT) - (unsigned)((b * (b - 1)) >> 1);
}

__device__ __forceinline__ void tile_decode(unsigned p, int& bi, int& bj) {
    const float A = (float)(2 * NT + 1);      // 129
    bi = (int)((A - sqrtf(A * A - 8.0f * (float)p)) * 0.5f);
    if (bi < 0) bi = 0;
    while (rowstart(bi + 1) <= p) ++bi;
    while (rowstart(bi) > p) --bi;
    bj = bi + (int)(p - rowstart(bi));
}

// compact decode for iter 8: only tiles with bj >= BI8 (484 total)
__device__ __forceinline__ void tile_decode_m2(unsigned p, int& bi, int& bj) {
    if (p < (unsigned)(BI8 * (NT - BI8))) {   // p < 448
        bi = (int)(p >> 3);
        bj = BI8 + (int)(p & 7u);
    } else {
        unsigned q = p - (unsigned)(BI8 * (NT - BI8));
        int b2 = 0;                            // 8-row triangle corner
        while ((unsigned)((b2 + 1) * 8 - ((b2 + 1) * b2) / 2) <= q) ++b2;
        bi = BI8 + b2;
        bj = bi + (int)(q - (unsigned)(b2 * 8 - (b2 * (b2 - 1)) / 2));
    }
}

__device__ __forceinline__ uint4 pack8(const float* v) {
    uint4 pk;
    ushort* us = (ushort*)&pk;
    #pragma unroll
    for (int d = 0; d < 8; ++d) us[d] = __half_as_ushort(__float2half_rn(v[d]));
    return pk;
}

__device__ __forceinline__ void sel8(float4 fA, float4 fB, float4 fC, int sel,
                                     float* v) {
    if (sel == 0) {
        v[0]=fA.x; v[1]=fA.y; v[2]=fA.z; v[3]=fA.w;
        v[4]=fB.x; v[5]=fB.y; v[6]=fB.z; v[7]=fB.w;
    } else if (sel == 1) {
        v[0]=fA.y; v[1]=fA.z; v[2]=fA.w; v[3]=fB.x;
        v[4]=fB.y; v[5]=fB.z; v[6]=fB.w; v[7]=fC.x;
    } else if (sel == 2) {
        v[0]=fA.z; v[1]=fA.w; v[2]=fB.x; v[3]=fB.y;
        v[4]=fB.z; v[5]=fB.w; v[6]=fC.x; v[7]=fC.y;
    } else {
        v[0]=fA.w; v[1]=fB.x; v[2]=fB.y; v[3]=fB.z;
        v[4]=fB.w; v[5]=fC.x; v[6]=fC.y; v[7]=fC.z;
    }
}

// ---- one-time f32 triangle -> fp16 padded triangle, ROW-WISE streaming ----
// Block b handles rows b and 8191-b. Head (to the 64-half boundary)
// elementwise; then threads stride aligned 8-half chunks — every 8-thread
// group writes one complete 128B line (no partial-line RMW).
__global__ __launch_bounds__(256) void conv_kernel(const float* __restrict__ w,
                                                   __half* __restrict__ w16) {
    int t = threadIdx.x;
    #pragma unroll
    for (int q = 0; q < 2; ++q) {
        int r = (q == 0) ? (int)blockIdx.x : (T - 1 - (int)blockIdx.x);
        int j1 = r + 1;
        int jA = (j1 + 63) & ~63;               // first 128B-aligned chunk col
        unsigned offr = triidx((unsigned)r, (unsigned)j1);  // row start in w
        int cr = crow64(r);
        if (t < jA - j1)                        // head (<64 elems)
            w16[cr + j1 + t] = __float2half_rn(w[offr + (unsigned)t]);
        if (jA >= T) continue;
        unsigned baseA = offr + (unsigned)(jA - j1);        // triidx(r, jA)
        int sel = (int)(baseA & 3u);            // uniform per row
        for (int j8 = jA + t * 8; j8 + 8 <= T; j8 += 8 * 256) {
            unsigned a0 = (baseA + (unsigned)(j8 - jA)) & ~3u;
            float4 fA = *(const float4*)(w + a0);
            float4 fB = *(const float4*)(w + a0 + 4);
            float4 fC = *(const float4*)(w + a0 + 8);
            float v[8];
            sel8(fA, fB, fC, sel, v);
            *(uint4*)(w16 + (cr + j8)) = pack8(v);
        }
    }
}

// init: build s0 (raw initial state, no tanh) and zero the 8 y accumulators.
__global__ __launch_bounds__(256) void init_kernel(const float* __restrict__ in,
                                                   float* __restrict__ s0,
                                                   float* __restrict__ y) {
    int n = blockIdx.x * 256 + threadIdx.x;
    if (n < T) s0[n] = (n < IN) ? in[n] : 0.0f;
    if (n < NPROP * T) y[n] = 0.0f;
}

// ---- fused symmetric tile pass (R14 body) ----
// mode 0: full. mode 1: iter1 (grid 904, bi<16; row side live only bj<16).
// mode 2: iter8 (compact grid 484, all tiles have bj>=56).
// State: sp ? sp[idx] : tanh(yprev[idx] + bv[idx]).
__global__ __launch_bounds__(256) void sym_kernel(const __half* __restrict__ w16,
                                                  const float* __restrict__ sp,
                                                  const float* __restrict__ yprev,
                                                  const float* __restrict__ bv,
                                                  float* __restrict__ y, int mode) {
    __shared__ float sIl[TILE], sJl[TILE];
    __shared__ float colpart[4][TILE];

    int bi, bj;
    if (mode == 2) tile_decode_m2(blockIdx.x, bi, bj);
    else           tile_decode(blockIdx.x, bi, bj);
    bool doRow = (mode == 0) ? true
               : (mode == 1) ? (bj < IN / TILE)
                             : (bi >= BI8);

    int i0 = bi * TILE, j0 = bj * TILE;
    int t = threadIdx.x;
    {
        int idx = (t < TILE) ? (i0 + t) : (j0 + (t - TILE));
        float sval = sp ? sp[idx] : tanhf(yprev[idx] + bv[idx]);
        if (t < TILE) sIl[t] = sval;
        else          sJl[t - TILE] = sval;
    }
    __syncthreads();

    int l = t & 63, wv = t >> 6;
    int g = l & 15, ro = l >> 4;
    int cbase = j0 + g * 8;

    float sjv[8];
    #pragma unroll
    for (int d = 0; d < 8; ++d) sjv[d] = sJl[g * 8 + d];
    float colacc[8] = {0.f, 0.f, 0.f, 0.f, 0.f, 0.f, 0.f, 0.f};

    #pragma unroll
    for (int k = 0; k < 8; ++k) {
        int rr = wv * 32 + k * 4 + ro;
        int r  = i0 + rr;
        // aligned uint4: crow64(r)%64==0, cbase%8==0. Sub-diagonal slots in
        // diag tiles read in-allocation garbage and are masked below.
        uint4 wq = *(const uint4*)(w16 + (crow64(r) + cbase));
        const __half2* h2 = (const __half2*)&wq;
        float2 f0 = __half22float2(h2[0]);
        float2 f1 = __half22float2(h2[1]);
        float2 f2 = __half22float2(h2[2]);
        float2 f3 = __half22float2(h2[3]);
        float wf[8] = {f0.x, f0.y, f1.x, f1.y, f2.x, f2.y, f3.x, f3.y};

        float si = sIl[rr];
        float rp = 0.0f;
        #pragma unroll
        for (int d = 0; d < 8; ++d) {
            float we = (cbase + d > r) ? wf[d] : 0.0f;   // strict upper only
            colacc[d] = fmaf(we, si, colacc[d]);
            rp        = fmaf(we, sjv[d], rp);
        }
        if (doRow) {
            rp += __shfl_xor(rp, 1, 64);
            rp += __shfl_xor(rp, 2, 64);
            rp += __shfl_xor(rp, 4, 64);
            rp += __shfl_xor(rp, 8, 64);
            if (g == 0) atomicAdd(&y[r], rp);
        }
    }

    #pragma unroll
    for (int d = 0; d < 8; ++d) {
        colacc[d] += __shfl_xor(colacc[d], 16, 64);
        colacc[d] += __shfl_xor(colacc[d], 32, 64);
    }
    if (l < 16) {
        #pragma unroll
        for (int d = 0; d < 8; ++d) colpart[wv][g * 8 + d] = colacc[d];
    }
    __syncthreads();
    if (t < TILE) {
        float c = colpart[0][t] + colpart[1][t] + colpart[2][t] + colpart[3][t];
        atomicAdd(&y[j0 + t], c);
    }
}

__global__ __launch_bounds__(256) void actout_kernel(const float* __restrict__ b,
                                                     const float* __restrict__ y,
                                                     float* __restrict__ o) {
    int n = blockIdx.x * 256 + threadIdx.x;
    if (n < OUT) o[n] = tanhf(y[T - OUT + n] + b[T - OUT + n]);
}

extern "C" void kernel_launch(void* const* d_in, const int* in_sizes, int n_in,
                              void* d_out, int out_size, void* d_ws, size_t ws_size,
                              hipStream_t stream) {
    const float* in = (const float*)d_in[0];   // inputs [2048]
    const float* w  = (const float*)d_in[1];   // w_flat [T*(T-1)/2] f32
    const float* b  = (const float*)d_in[2];   // b [8192] f32
    float* out = (float*)d_out;                // [1024] f32

    __half* w16 = (__half*)d_ws;                               // 67.63 MB
    float*  s0  = (float*)((char*)d_ws + W16_ALLOC * sizeof(__half));
    float*  y   = s0 + T;                      // 8 accumulators, y + it*T

    conv_kernel<<<T / 2, 256, 0, stream>>>(w, w16);
    init_kernel<<<NPROP * T / 256, 256, 0, stream>>>(in, s0, y);

    // iter 1: tiles bi<16 (contiguous p < 904); state = s0 (no tanh)
    sym_kernel<<<rowstart(IN / TILE), 256, 0, stream>>>(w16, s0, nullptr, nullptr,
                                                        y, 1);
    // iters 2..7: state = tanh(y[it-2] + b), accumulate into y[it-1]
    for (int it = 1; it < NPROP - 1; ++it) {
        sym_kernel<<<NTILES, 256, 0, stream>>>(w16, nullptr, y + (it - 1) * T, b,
                                               y + it * T, 0);
    }
    // iter 8: compact grid — only the 484 tiles with bj >= 56
    sym_kernel<<<N8, 256, 0, stream>>>(w16, nullptr, y + (NPROP - 2) * T, b,
                                       y + (NPROP - 1) * T, 2);
    actout_kernel<<<OUT / 256, 256, 0, stream>>>(b, y + (NPROP - 1) * T, out);
}